// Round 6
// baseline (219.421 us; speedup 1.0000x reference)
//
#include <hip/hip_runtime.h>

#define N_NODES 100000
#define DIM 8
#define NB 128                 // nodes per bucket
#define BSHIFT 7               // log2(NB)
#define NBUCKETS ((N_NODES + NB - 1) / NB)   // 782
#define LSROW (NBUCKETS + 1)   // localStart row stride (783)
#define G1 2048                // local-sort blocks
#define ESPAN_MAX 3200         // max edges per local-sort block (LDS cap)
#define CAP 9728               // max edges per bucket staged in LDS (mean 8184)

// ---------------- fallback (atomic path) ----------------
__global__ void init_neg_kernel(const float* __restrict__ x,
                                float* __restrict__ out, int n4) {
    int i = blockIdx.x * blockDim.x + threadIdx.x;
    if (i < n4) {
        float4 v = reinterpret_cast<const float4*>(x)[i];
        float4 o; o.x = -v.x; o.y = -v.y; o.z = -v.z; o.w = -v.w;
        reinterpret_cast<float4*>(out)[i] = o;
    }
}

__global__ void edge_scatter_atomic(const float* __restrict__ x,
                                    const int* __restrict__ row,
                                    const int* __restrict__ col,
                                    const float* __restrict__ w,
                                    float* __restrict__ out, int nE) {
    int e = blockIdx.x * blockDim.x + threadIdx.x;
    if (e >= nE) return;
    int r = row[e], c = col[e];
    float we = w[e];
    const float4* xr = reinterpret_cast<const float4*>(x + (size_t)r * DIM);
    const float4* xc = reinterpret_cast<const float4*>(x + (size_t)c * DIM);
    float4 a0 = xr[0], a1 = xr[1], b0 = xc[0], b1 = xc[1];
    float* o = out + (size_t)c * DIM;
    atomicAdd(o + 0, (a0.x - b0.x) * we); atomicAdd(o + 1, (a0.y - b0.y) * we);
    atomicAdd(o + 2, (a0.z - b0.z) * we); atomicAdd(o + 3, (a0.w - b0.w) * we);
    atomicAdd(o + 4, (a1.x - b1.x) * we); atomicAdd(o + 5, (a1.y - b1.y) * we);
    atomicAdd(o + 6, (a1.z - b1.z) * we); atomicAdd(o + 7, (a1.w - b1.w) * we);
}

// ---------------- sorted pipeline (R6) ----------------

// Pass 1: fused count + local counting-sort + block-contiguous flush.
// Each block sorts its espan edges by bucket into LDS, writes them to its OWN
// contiguous payloadA region (fully coalesced), and emits localStart[blk][b].
__global__ __launch_bounds__(512) void local_sort_kernel(
        const int* __restrict__ row,
        const int* __restrict__ col,
        const float* __restrict__ w,
        int nE, int espan,
        uint2* __restrict__ payloadA,
        unsigned* __restrict__ localStart) {
    __shared__ uint2 stage[ESPAN_MAX];      // 25.6 KB
    __shared__ unsigned cnt[NBUCKETS];      // 3.1 KB
    __shared__ unsigned part[512];          // 2 KB
    int t = threadIdx.x, blk = blockIdx.x;
    long e0 = (long)blk * espan;
    int n = (int)((long)nE - e0 > (long)espan ? espan : (long)nE - e0);
    if (n < 0) n = 0;

    for (int i = t; i < NBUCKETS; i += 512) cnt[i] = 0;
    __syncthreads();

    for (int k = t; k < n; k += 512)
        atomicAdd(&cnt[((unsigned)col[e0 + k]) >> BSHIFT], 1u);
    __syncthreads();

    // exclusive scan over 782 buckets (2 per thread)
    unsigned c0 = (2 * t < NBUCKETS) ? cnt[2 * t] : 0u;
    unsigned c1 = (2 * t + 1 < NBUCKETS) ? cnt[2 * t + 1] : 0u;
    part[t] = c0 + c1; __syncthreads();
    for (int off = 1; off < 512; off <<= 1) {
        unsigned u = (t >= off) ? part[t - off] : 0u;
        __syncthreads();
        part[t] += u; __syncthreads();
    }
    unsigned base = part[t] - (c0 + c1);

    size_t lrow = (size_t)blk * LSROW;
    if (2 * t < NBUCKETS)     localStart[lrow + 2 * t] = base;
    if (2 * t + 1 < NBUCKETS) localStart[lrow + 2 * t + 1] = base + c0;
    if (t == 0)               localStart[lrow + NBUCKETS] = (unsigned)n;
    __syncthreads();
    if (2 * t < NBUCKETS)     cnt[2 * t] = base;          // cursors
    if (2 * t + 1 < NBUCKETS) cnt[2 * t + 1] = base + c0;
    __syncthreads();

    for (int k = t; k < n; k += 512) {
        unsigned c = (unsigned)col[e0 + k];
        unsigned b = c >> BSHIFT;
        unsigned pos = atomicAdd(&cnt[b], 1u);
        stage[pos] = make_uint2(((unsigned)row[e0 + k] << BSHIFT) | (c & (NB - 1)),
                                __float_as_uint(w[e0 + k]));
    }
    __syncthreads();

    // block-contiguous coalesced flush
    for (int k = t; k < n; k += 512)
        payloadA[e0 + k] = stage[k];
}

// Pass 2a: per-bucket totals from localStart diffs
__global__ __launch_bounds__(256) void bucket_total_kernel(
        const unsigned* __restrict__ localStart,
        unsigned* __restrict__ bucketTotal) {
    __shared__ unsigned sc[256];
    int b = blockIdx.x;
    unsigned s = 0;
    for (int blk = threadIdx.x; blk < G1; blk += 256) {
        size_t lrow = (size_t)blk * LSROW;
        s += localStart[lrow + b + 1] - localStart[lrow + b];
    }
    sc[threadIdx.x] = s; __syncthreads();
    for (int off = 128; off > 0; off >>= 1) {
        if (threadIdx.x < off) sc[threadIdx.x] += sc[threadIdx.x + off];
        __syncthreads();
    }
    if (threadIdx.x == 0) bucketTotal[b] = sc[0];
}

// Pass 2b: exclusive scan over bucket totals (single block)
__global__ __launch_bounds__(1024) void bucket_scan_kernel(
        const unsigned* __restrict__ bucketTotal,
        unsigned* __restrict__ bucketStart) {
    __shared__ unsigned sc[1024];
    int t = threadIdx.x;
    unsigned v = (t < NBUCKETS) ? bucketTotal[t] : 0u;
    sc[t] = v; __syncthreads();
    for (int off = 1; off < 1024; off <<= 1) {
        unsigned u = (t >= off) ? sc[t - off] : 0u;
        __syncthreads();
        sc[t] += u; __syncthreads();
    }
    if (t < NBUCKETS) bucketStart[t] = sc[t] - v;
    if (t == NBUCKETS - 1) bucketStart[NBUCKETS] = sc[t];
}

// Pass 3: per-bucket gather of its G1 runs, in-bucket counting sort by node,
// coalesced flush to payloadB, emit per-node CSR offsets.
__global__ __launch_bounds__(512) void bucket_sort_kernel(
        const uint2* __restrict__ payloadA,
        const unsigned* __restrict__ localStart,
        const unsigned* __restrict__ bucketStart,
        unsigned* __restrict__ nodeStart,
        uint2* __restrict__ payloadB,
        int espan) {
    __shared__ uint2 stage[CAP];            // 76 KB
    __shared__ unsigned part[512];
    __shared__ unsigned cnt[NB];
    __shared__ unsigned scanb[NB];
    int b = blockIdx.x, t = threadIdx.x;

    // 4 runs per thread: load start/len, keep in regs
    unsigned rstart[4], rlen[4];
    unsigned mysum = 0;
    #pragma unroll
    for (int j = 0; j < 4; ++j) {
        int blk = 4 * t + j;
        size_t lrow = (size_t)blk * LSROW;
        unsigned s0 = localStart[lrow + b];
        unsigned s1 = localStart[lrow + b + 1];
        rstart[j] = s0;
        rlen[j] = s1 - s0;
        mysum += rlen[j];
    }
    part[t] = mysum; __syncthreads();
    for (int off = 1; off < 512; off <<= 1) {
        unsigned u = (t >= off) ? part[t - off] : 0u;
        __syncthreads();
        part[t] += u; __syncthreads();
    }
    unsigned nTot = part[511];

    if (t < NB) cnt[t] = 0;
    __syncthreads();

    // count pass over this bucket's runs
    #pragma unroll
    for (int j = 0; j < 4; ++j) {
        size_t g = (size_t)(4 * t + j) * espan + rstart[j];
        for (unsigned i = 0; i < rlen[j]; ++i)
            atomicAdd(&cnt[payloadA[g + i].x & (NB - 1)], 1u);
    }
    __syncthreads();

    // scan 128 node counts
    if (t < NB) scanb[t] = cnt[t];
    __syncthreads();
    for (int off = 1; off < NB; off <<= 1) {
        unsigned v = 0;
        if (t < NB && t >= off) v = scanb[t - off];
        __syncthreads();
        if (t < NB) scanb[t] += v;
        __syncthreads();
    }
    unsigned outBase = bucketStart[b];
    if (t < NB) {
        unsigned ex = scanb[t] - cnt[t];
        nodeStart[b * NB + t] = outBase + ex;
        cnt[t] = ex;                       // cursor (bucket-local)
    }
    __syncthreads();

    bool ovf = nTot > CAP;                 // freak case: direct global writes

    // scatter pass: sorted-by-node into LDS stage (or global if overflow)
    #pragma unroll
    for (int j = 0; j < 4; ++j) {
        size_t g = (size_t)(4 * t + j) * espan + rstart[j];
        for (unsigned i = 0; i < rlen[j]; ++i) {
            uint2 p = payloadA[g + i];
            unsigned node = p.x & (NB - 1);
            unsigned pos = atomicAdd(&cnt[node], 1u);
            uint2 v = make_uint2(p.x >> BSHIFT, p.y);
            if (!ovf) stage[pos] = v;
            else      payloadB[outBase + pos] = v;
        }
    }
    __syncthreads();

    if (!ovf)
        for (unsigned k = t; k < nTot; k += 512)
            payloadB[outBase + k] = stage[k];
}

// Pass 4: pure-register CSR gather. thread = (node, dim). No atomics.
__global__ __launch_bounds__(256) void csr_gather_kernel(
        const float* __restrict__ x,
        const uint2* __restrict__ payloadB,
        const unsigned* __restrict__ nodeStart,
        float* __restrict__ out) {
    int gid = blockIdx.x * 256 + threadIdx.x;
    int n = gid >> 3, d = gid & 7;
    int e = (int)nodeStart[n], eEnd = (int)nodeStart[n + 1];
    float xc = x[(size_t)n * DIM + d];
    float a0 = 0.f, a1 = 0.f;
    for (; e + 4 <= eEnd; e += 4) {
        uint2 p0 = payloadB[e];
        uint2 p1 = payloadB[e + 1];
        uint2 p2 = payloadB[e + 2];
        uint2 p3 = payloadB[e + 3];
        float s0 = x[(size_t)p0.x * DIM + d];
        float s1 = x[(size_t)p1.x * DIM + d];
        float s2 = x[(size_t)p2.x * DIM + d];
        float s3 = x[(size_t)p3.x * DIM + d];
        a0 += (s0 - xc) * __uint_as_float(p0.y);
        a1 += (s1 - xc) * __uint_as_float(p1.y);
        a0 += (s2 - xc) * __uint_as_float(p2.y);
        a1 += (s3 - xc) * __uint_as_float(p3.y);
    }
    for (; e < eEnd; ++e) {
        uint2 p = payloadB[e];
        a0 += (x[(size_t)p.x * DIM + d] - xc) * __uint_as_float(p.y);
    }
    out[(size_t)n * DIM + d] = a0 + a1 - xc;
}

extern "C" void kernel_launch(void* const* d_in, const int* in_sizes, int n_in,
                              void* d_out, int out_size, void* d_ws, size_t ws_size,
                              hipStream_t stream) {
    const float* x   = (const float*)d_in[0];
    const int*   row = (const int*)d_in[1];
    const int*   col = (const int*)d_in[2];
    const float* w   = (const float*)d_in[3];
    float* out = (float*)d_out;
    int nE = in_sizes[1];
    int n4 = out_size / 4;

    int espan = (nE + G1 - 1) / G1;

    size_t off_payloadA  = 0;
    size_t off_localSt   = off_payloadA + (size_t)G1 * espan * sizeof(uint2);
    size_t off_total     = off_localSt  + (size_t)G1 * LSROW * 4;
    size_t off_start     = off_total    + (size_t)NBUCKETS * 4;
    size_t off_nodeStart = off_start    + (size_t)(NBUCKETS + 1) * 4;
    size_t off_payloadB  = off_nodeStart+ (size_t)(NBUCKETS * NB + 2) * 4;
    size_t need          = off_payloadB + (size_t)nE * sizeof(uint2);

    if (ws_size < need || espan > ESPAN_MAX) {
        init_neg_kernel<<<(n4 + 255) / 256, 256, 0, stream>>>(x, out, n4);
        edge_scatter_atomic<<<(nE + 255) / 256, 256, 0, stream>>>(x, row, col, w, out, nE);
        return;
    }

    char* p = (char*)d_ws;
    uint2*    payloadA    = (uint2*)(p + off_payloadA);
    unsigned* localStart  = (unsigned*)(p + off_localSt);
    unsigned* bucketTotal = (unsigned*)(p + off_total);
    unsigned* bucketStart = (unsigned*)(p + off_start);
    unsigned* nodeStart   = (unsigned*)(p + off_nodeStart);
    uint2*    payloadB    = (uint2*)(p + off_payloadB);

    local_sort_kernel<<<G1, 512, 0, stream>>>(row, col, w, nE, espan,
                                              payloadA, localStart);
    bucket_total_kernel<<<NBUCKETS, 256, 0, stream>>>(localStart, bucketTotal);
    bucket_scan_kernel<<<1, 1024, 0, stream>>>(bucketTotal, bucketStart);
    bucket_sort_kernel<<<NBUCKETS, 512, 0, stream>>>(payloadA, localStart,
                                                     bucketStart, nodeStart,
                                                     payloadB, espan);
    csr_gather_kernel<<<(N_NODES * DIM) / 256, 256, 0, stream>>>(x, payloadB,
                                                                 nodeStart, out);
}

// Round 7
// 154.914 us; speedup vs baseline: 1.4164x; 1.4164x over previous
//
#include <hip/hip_runtime.h>

#define N_NODES 100000
#define DIM 8
#define NB 128                 // nodes per bucket
#define BSHIFT 7               // log2(NB)
#define NBUCKETS ((N_NODES + NB - 1) / NB)   // 782
#define G1 2048                // hist/scatter blocks
#define ESPAN_MAX 3328         // max edges per scatter block (LDS stage cap)
#define SCT 512                // scatter block threads
#define CAP 9728               // max edges per bucket in LDS stage (mean 8184, 17 sigma margin)

// ---------------- fallback (atomic path) ----------------
__global__ void init_neg_kernel(const float* __restrict__ x,
                                float* __restrict__ out, int n4) {
    int i = blockIdx.x * blockDim.x + threadIdx.x;
    if (i < n4) {
        float4 v = reinterpret_cast<const float4*>(x)[i];
        float4 o; o.x = -v.x; o.y = -v.y; o.z = -v.z; o.w = -v.w;
        reinterpret_cast<float4*>(out)[i] = o;
    }
}

__global__ void edge_scatter_atomic(const float* __restrict__ x,
                                    const int* __restrict__ row,
                                    const int* __restrict__ col,
                                    const float* __restrict__ w,
                                    float* __restrict__ out, int nE) {
    int e = blockIdx.x * blockDim.x + threadIdx.x;
    if (e >= nE) return;
    int r = row[e], c = col[e];
    float we = w[e];
    const float4* xr = reinterpret_cast<const float4*>(x + (size_t)r * DIM);
    const float4* xc = reinterpret_cast<const float4*>(x + (size_t)c * DIM);
    float4 a0 = xr[0], a1 = xr[1], b0 = xc[0], b1 = xc[1];
    float* o = out + (size_t)c * DIM;
    atomicAdd(o + 0, (a0.x - b0.x) * we); atomicAdd(o + 1, (a0.y - b0.y) * we);
    atomicAdd(o + 2, (a0.z - b0.z) * we); atomicAdd(o + 3, (a0.w - b0.w) * we);
    atomicAdd(o + 4, (a1.x - b1.x) * we); atomicAdd(o + 5, (a1.y - b1.y) * we);
    atomicAdd(o + 6, (a1.z - b1.z) * we); atomicAdd(o + 7, (a1.w - b1.w) * we);
}

// ---------------- sorted pipeline (R7) ----------------
// blockHist / blockOffs layout: [blk][bucket]  (blk*NBUCKETS + b)

// Pass 1: per-block LDS histogram of col buckets
__global__ __launch_bounds__(256) void hist_kernel(const int* __restrict__ col,
                                                   int nE, int espan,
                                                   unsigned* __restrict__ blockHist) {
    __shared__ unsigned hist[NBUCKETS];
    for (int i = threadIdx.x; i < NBUCKETS; i += 256) hist[i] = 0;
    __syncthreads();
    long e0 = (long)blockIdx.x * espan;
    long e1 = e0 + espan; if (e1 > nE) e1 = nE;
    for (long e = e0 + threadIdx.x; e < e1; e += 256)
        atomicAdd(&hist[((unsigned)col[e]) >> BSHIFT], 1u);
    __syncthreads();
    for (int b = threadIdx.x; b < NBUCKETS; b += 256)
        blockHist[(size_t)blockIdx.x * NBUCKETS + b] = hist[b];
}

// Pass 2a: per-bucket totals (sum over blocks)
__global__ __launch_bounds__(256) void bucket_total_kernel(const unsigned* __restrict__ blockHist,
                                                           unsigned* __restrict__ bucketTotal) {
    __shared__ unsigned sc[256];
    int b = blockIdx.x;
    unsigned s = 0;
    for (int i = threadIdx.x; i < G1; i += 256) s += blockHist[(size_t)i * NBUCKETS + b];
    sc[threadIdx.x] = s; __syncthreads();
    for (int off = 128; off > 0; off >>= 1) {
        if (threadIdx.x < off) sc[threadIdx.x] += sc[threadIdx.x + off];
        __syncthreads();
    }
    if (threadIdx.x == 0) bucketTotal[b] = sc[0];
}

// Pass 2b: exclusive scan over bucket totals (single block)
__global__ __launch_bounds__(1024) void bucket_scan_kernel(const unsigned* __restrict__ bucketTotal,
                                                           unsigned* __restrict__ bucketStart) {
    __shared__ unsigned sc[1024];
    int t = threadIdx.x;
    unsigned v = (t < NBUCKETS) ? bucketTotal[t] : 0u;
    sc[t] = v; __syncthreads();
    for (int off = 1; off < 1024; off <<= 1) {
        unsigned u = (t >= off) ? sc[t - off] : 0u;
        __syncthreads();
        sc[t] += u; __syncthreads();
    }
    if (t < NBUCKETS) bucketStart[t] = sc[t] - v;
    if (t == NBUCKETS - 1) bucketStart[NBUCKETS] = sc[t];
}

// Pass 2c: per-bucket exclusive scan over the G1 block entries (+bucket base)
__global__ __launch_bounds__(256) void block_offs_kernel(const unsigned* __restrict__ blockHist,
                                                         const unsigned* __restrict__ bucketStart,
                                                         unsigned* __restrict__ blockOffs) {
    __shared__ unsigned part[256];
    int b = blockIdx.x, t = threadIdx.x;
    const int C = G1 / 256;            // 8 entries per thread
    unsigned vv[C], s = 0;
    #pragma unroll
    for (int j = 0; j < C; ++j) {
        vv[j] = blockHist[(size_t)(t * C + j) * NBUCKETS + b];
        s += vv[j];
    }
    part[t] = s; __syncthreads();
    for (int off = 1; off < 256; off <<= 1) {
        unsigned u = (t >= off) ? part[t - off] : 0u;
        __syncthreads();
        part[t] += u; __syncthreads();
    }
    unsigned base = part[t] - s + bucketStart[b];
    #pragma unroll
    for (int j = 0; j < C; ++j) {
        blockOffs[(size_t)(t * C + j) * NBUCKETS + b] = base;
        base += vv[j];
    }
}

// Pass 3: block-local counting sort + coalesced run-flush to bucket-major payloadA.
__global__ __launch_bounds__(SCT) void scatter_local_kernel(
        const int* __restrict__ row,
        const int* __restrict__ col,
        const float* __restrict__ w,
        int nE, int espan,
        const unsigned* __restrict__ blockOffs,
        uint2* __restrict__ payload) {
    __shared__ uint2 stage[ESPAN_MAX];           // 26.6 KB
    __shared__ unsigned short sbkt[ESPAN_MAX];   // 6.7 KB
    __shared__ unsigned cnt[NBUCKETS];           // 3.1 KB
    __shared__ unsigned lstart[NBUCKETS];        // 3.1 KB
    __shared__ unsigned gbase[NBUCKETS];         // 3.1 KB
    __shared__ unsigned part[SCT];               // 2 KB

    int t = threadIdx.x, blk = blockIdx.x;
    long e0 = (long)blk * espan;
    int n = (int)(((long)nE - e0 > (long)espan) ? espan : ((long)nE - e0));
    if (n < 0) n = 0;

    for (int i = t; i < NBUCKETS; i += SCT) cnt[i] = 0;
    __syncthreads();

    for (int k = t; k < n; k += SCT)
        atomicAdd(&cnt[((unsigned)col[e0 + k]) >> BSHIFT], 1u);
    __syncthreads();

    // exclusive scan of 782 bucket counts (2 per thread)
    unsigned c0 = (2 * t < NBUCKETS) ? cnt[2 * t] : 0u;
    unsigned c1 = (2 * t + 1 < NBUCKETS) ? cnt[2 * t + 1] : 0u;
    part[t] = c0 + c1; __syncthreads();
    for (int off = 1; off < SCT; off <<= 1) {
        unsigned u = (t >= off) ? part[t - off] : 0u;
        __syncthreads();
        part[t] += u; __syncthreads();
    }
    unsigned cbase = part[t] - (c0 + c1);
    if (2 * t < NBUCKETS)     lstart[2 * t] = cbase;
    if (2 * t + 1 < NBUCKETS) lstart[2 * t + 1] = cbase + c0;
    __syncthreads();
    for (int i = t; i < NBUCKETS; i += SCT) cnt[i] = lstart[i];  // cursors
    for (int b = t; b < NBUCKETS; b += SCT)
        gbase[b] = blockOffs[(size_t)blk * NBUCKETS + b];        // coalesced row
    __syncthreads();

    for (int k = t; k < n; k += SCT) {
        unsigned c = (unsigned)col[e0 + k];
        unsigned b = c >> BSHIFT;
        unsigned pos = atomicAdd(&cnt[b], 1u);
        stage[pos] = make_uint2(((unsigned)row[e0 + k] << BSHIFT) | (c & (NB - 1)),
                                __float_as_uint(w[e0 + k]));
        sbkt[pos] = (unsigned short)b;
    }
    __syncthreads();

    // flush: per-bucket runs -> bucket-major global positions (run-coalesced)
    for (int k = t; k < n; k += SCT) {
        unsigned b = sbkt[k];
        unsigned gpos = gbase[b] + ((unsigned)k - lstart[b]);
        payload[gpos] = stage[k];
    }
}

// Pass 4 (fused): per-bucket in-LDS node sort + register gather, no payloadB.
__global__ __launch_bounds__(512) void bucket_sort_gather_kernel(
        const float* __restrict__ x,
        const uint2* __restrict__ payloadA,
        const unsigned* __restrict__ bucketStart,
        float* __restrict__ out) {
    __shared__ uint2 stage[CAP];          // 76 KB
    __shared__ unsigned cnt[NB];
    __shared__ unsigned scanb[NB];
    __shared__ unsigned exs[NB + 1];
    int b = blockIdx.x, t = threadIdx.x;
    int e0 = (int)bucketStart[b], e1 = (int)bucketStart[b + 1];
    int n = e1 - e0;

    if (t < NB) cnt[t] = 0;
    __syncthreads();

    if (n <= CAP) {
        // count pass (coalesced payload read)
        for (int k = t; k < n; k += 512)
            atomicAdd(&cnt[payloadA[e0 + k].x & (NB - 1)], 1u);
        __syncthreads();
        if (t < NB) scanb[t] = cnt[t];
        __syncthreads();
        for (int off = 1; off < NB; off <<= 1) {
            unsigned v = 0;
            if (t < NB && t >= off) v = scanb[t - off];
            __syncthreads();
            if (t < NB) scanb[t] += v;
            __syncthreads();
        }
        if (t < NB) {
            unsigned ex = scanb[t] - cnt[t];
            exs[t] = ex;
            cnt[t] = ex;                  // cursor
        }
        if (t == 0) exs[NB] = (unsigned)n;
        __syncthreads();

        // scatter pass: sorted-by-node into LDS stage (payload re-read, L2-hot)
        for (int k = t; k < n; k += 512) {
            uint2 p = payloadA[e0 + k];
            unsigned node = p.x & (NB - 1);
            unsigned pos = atomicAdd(&cnt[node], 1u);
            stage[pos] = make_uint2(p.x >> BSHIFT, p.y);
        }
        __syncthreads();

        // register gather from LDS stage; out = acc - x, coalesced write
        for (int slot = t; slot < NB * DIM; slot += 512) {
            int node = slot >> 3, d = slot & 7;
            int gn = b * NB + node;
            if (gn >= N_NODES) continue;
            float xc = x[(size_t)gn * DIM + d];
            int e = (int)exs[node], eEnd = (int)exs[node + 1];
            float a0 = 0.f, a1 = 0.f;
            for (; e + 4 <= eEnd; e += 4) {
                uint2 p0 = stage[e];
                uint2 p1 = stage[e + 1];
                uint2 p2 = stage[e + 2];
                uint2 p3 = stage[e + 3];
                float s0 = x[(size_t)p0.x * DIM + d];
                float s1 = x[(size_t)p1.x * DIM + d];
                float s2 = x[(size_t)p2.x * DIM + d];
                float s3 = x[(size_t)p3.x * DIM + d];
                a0 += (s0 - xc) * __uint_as_float(p0.y);
                a1 += (s1 - xc) * __uint_as_float(p1.y);
                a0 += (s2 - xc) * __uint_as_float(p2.y);
                a1 += (s3 - xc) * __uint_as_float(p3.y);
            }
            for (; e < eEnd; ++e) {
                uint2 p = stage[e];
                a0 += (x[(size_t)p.x * DIM + d] - xc) * __uint_as_float(p.y);
            }
            out[(size_t)gn * DIM + d] = a0 + a1 - xc;
        }
    } else {
        // overflow (statistically impossible; correctness-only): init -x, then
        // global f32 atomics for this bucket.
        for (int slot = t; slot < NB * DIM; slot += 512) {
            int gn = b * NB + (slot >> 3);
            if (gn < N_NODES) {
                size_t gi = (size_t)b * NB * DIM + slot;
                out[gi] = -x[gi];
            }
        }
        __syncthreads();
        int d = t & 7, sub = t >> 3;
        for (int k = sub; k < n; k += 64) {
            uint2 p = payloadA[e0 + k];
            int node = (int)(p.x & (NB - 1));
            int r = (int)(p.x >> BSHIFT);
            int gn = b * NB + node;
            if (gn < N_NODES) {
                float xc = x[(size_t)gn * DIM + d];
                atomicAdd(&out[(size_t)gn * DIM + d],
                          (x[(size_t)r * DIM + d] - xc) * __uint_as_float(p.y));
            }
        }
    }
}

extern "C" void kernel_launch(void* const* d_in, const int* in_sizes, int n_in,
                              void* d_out, int out_size, void* d_ws, size_t ws_size,
                              hipStream_t stream) {
    const float* x   = (const float*)d_in[0];
    const int*   row = (const int*)d_in[1];
    const int*   col = (const int*)d_in[2];
    const float* w   = (const float*)d_in[3];
    float* out = (float*)d_out;
    int nE = in_sizes[1];
    int n4 = out_size / 4;

    int espan = (nE + G1 - 1) / G1;

    size_t off_payloadA  = 0;
    size_t off_blockHist = off_payloadA  + (size_t)nE * sizeof(uint2);
    size_t off_blockOffs = off_blockHist + (size_t)G1 * NBUCKETS * 4;
    size_t off_total     = off_blockOffs + (size_t)G1 * NBUCKETS * 4;
    size_t off_start     = off_total     + (size_t)NBUCKETS * 4;
    size_t need          = off_start     + (size_t)(NBUCKETS + 1) * 4;

    if (ws_size < need || espan > ESPAN_MAX) {
        init_neg_kernel<<<(n4 + 255) / 256, 256, 0, stream>>>(x, out, n4);
        edge_scatter_atomic<<<(nE + 255) / 256, 256, 0, stream>>>(x, row, col, w, out, nE);
        return;
    }

    char* p = (char*)d_ws;
    uint2*    payloadA    = (uint2*)(p + off_payloadA);
    unsigned* blockHist   = (unsigned*)(p + off_blockHist);
    unsigned* blockOffs   = (unsigned*)(p + off_blockOffs);
    unsigned* bucketTotal = (unsigned*)(p + off_total);
    unsigned* bucketStart = (unsigned*)(p + off_start);

    hist_kernel<<<G1, 256, 0, stream>>>(col, nE, espan, blockHist);
    bucket_total_kernel<<<NBUCKETS, 256, 0, stream>>>(blockHist, bucketTotal);
    bucket_scan_kernel<<<1, 1024, 0, stream>>>(bucketTotal, bucketStart);
    block_offs_kernel<<<NBUCKETS, 256, 0, stream>>>(blockHist, bucketStart, blockOffs);
    scatter_local_kernel<<<G1, SCT, 0, stream>>>(row, col, w, nE, espan,
                                                 blockOffs, payloadA);
    bucket_sort_gather_kernel<<<NBUCKETS, 512, 0, stream>>>(x, payloadA,
                                                            bucketStart, out);
}